// Round 4
// baseline (206.257 us; speedup 1.0000x reference)
//
#include <hip/hip_runtime.h>
#include <math.h>

// Problem constants
#define BB 4
#define SS 4096
#define DD 64
#define HH 16
#define PI_C 3.1415f

// ---------------------------------------------------------------------------
// ws layout (bytes):
//   0        : pkv   fp32 [8][64bh][z*64+x]   8,388,608
//   8388608  : pkvs  fp32 [8][64bh][z*64+x]   8,388,608
//   16777216 : pks   fp32 [8][64bh][128]        262,144   (ksum|kssum)
//   17039360 : kvb   bf16 [64bh][z*64+x]        524,288
//   17563648 : kvsb  bf16                       524,288
//   18087936 : ksums fp32 [64bh][128]            32,768
//   18120704 : wT    bf16 wq|wk|wv|wd x 65536   524,288
//   total ~18.6 MB
// ---------------------------------------------------------------------------

typedef __attribute__((ext_vector_type(8))) short short8;   // 8 x bf16 frag
typedef __attribute__((ext_vector_type(4))) float f32x4;    // MFMA C/D frag

#define MFMA(a, b, c) __builtin_amdgcn_mfma_f32_16x16x32_bf16(a, b, c, 0, 0, 0)

__device__ __forceinline__ short f2bf(float f) {
    union { float f; unsigned u; } v; v.f = f;
    unsigned r = v.u + 0x7FFFu + ((v.u >> 16) & 1u);   // round-to-nearest-even
    return (short)(r >> 16);
}
__device__ __forceinline__ float bf2f(short s) {
    union { unsigned u; float f; } v;
    v.u = ((unsigned)(unsigned short)s) << 16;
    return v.f;
}
__device__ __forceinline__ short8 cvt8(float4 a, float4 b) {
    short8 r;
    r[0] = f2bf(a.x); r[1] = f2bf(a.y); r[2] = f2bf(a.z); r[3] = f2bf(a.w);
    r[4] = f2bf(b.x); r[5] = f2bf(b.y); r[6] = f2bf(b.z); r[7] = f2bf(b.w);
    return r;
}
__device__ __forceinline__ float elu1(float x) { return x > 0.f ? x + 1.f : __expf(x); }
__device__ __forceinline__ void st4(short* p, short a, short b, short c, short d) {
    union { uint2 u; short s[4]; } x;
    x.s[0] = a; x.s[1] = b; x.s[2] = c; x.s[3] = d;
    *reinterpret_cast<uint2*>(p) = x.u;
}

// ---------------------------------------------------------------------------
// Transpose + bf16-convert weights into per-head [out_col][in_dim] layout.
__global__ __launch_bounds__(256) void k_prep(
    const float* __restrict__ wq, const float* __restrict__ wk,
    const float* __restrict__ wv, const float* __restrict__ wd,
    short* __restrict__ dst)
{
    const int h = blockIdx.x, y = blockIdx.y, t = threadIdx.x;
    const float* src = (y == 0) ? wq : (y == 1) ? wk : (y == 2) ? wv : wd;
    const int rs = (y < 3) ? 1024 : 64;
    const size_t srcbase = (y < 3) ? (size_t)(h * 64) : (size_t)(h * 4096);
    short* dm = dst + (size_t)y * 65536 + (size_t)h * 4096;
#pragma unroll
    for (int j = 0; j < 4; ++j) {
        int idx = j * 1024 + t * 4;
        int r = idx >> 6, c = idx & 63;
        float4 v = *reinterpret_cast<const float4*>(src + (size_t)r * rs + srcbase + c);
        dm[(c + 0) * 64 + r] = f2bf(v.x);
        dm[(c + 1) * 64 + r] = f2bf(v.y);
        dm[(c + 2) * 64 + r] = f2bf(v.z);
        dm[(c + 3) * 64 + r] = f2bf(v.w);
    }
}

// ---------------------------------------------------------------------------
// Phase 1: 512 threads / 8 waves. Waves 0-3 project K rows, waves 4-7 project
// V rows (double-buffered 64-row tiles, 1 barrier per iter). kv GEMM: waves
// 0-3 accumulate kv (A=v'), waves 4-7 accumulate kvs (A=v'*sin), B=k'.
__global__ __launch_bounds__(512, 4) void k_phase1(
    const float* __restrict__ key, const float* __restrict__ value,
    const float* __restrict__ wk_b, const float* __restrict__ wv_b,
    const short* __restrict__ wkTb, const short* __restrict__ wvTb,
    float* __restrict__ pkv, float* __restrict__ pkvs,
    float* __restrict__ pks)
{
    const int chunk = blockIdx.x, h = blockIdx.y, b = blockIdx.z;
    const int t = threadIdx.x, w = t >> 6, l = t & 63;
    const int lane15 = l & 15, q8 = (l >> 4) * 8, q4 = (l >> 4) * 4;
    const int pw = w & 3;
    const bool isV = (w >= 4);

    __shared__ short kT[2][64 * 72];      // [x][s] bf16 k' tiles
    __shared__ short vT[2][64 * 72];      // [z][s] bf16 v' tiles
    __shared__ short vsT[2][64 * 72];     // [z][s] bf16 v'*sin tiles
    __shared__ float ssin[512];
    __shared__ float sb[128];             // wk_b | wv_b for this head
    __shared__ float sred[1024];

    // projection weight B-frags -> registers (one matrix per wave)
    const short* wsrc = (isV ? wvTb : wkTb) + (size_t)h * 4096;
    short8 bw[2][4];
#pragma unroll
    for (int kss = 0; kss < 2; ++kss)
#pragma unroll
        for (int nt = 0; nt < 4; ++nt)
            bw[kss][nt] = *reinterpret_cast<const short8*>(
                wsrc + (nt * 16 + lane15) * 64 + kss * 32 + q8);

    ssin[t] = __sinf(PI_C * (float)(chunk * 512 + t) * (1.f / 4096.f));
    if (t < 64) sb[t] = wk_b[h * 64 + t];
    else if (t < 128) sb[t] = wv_b[h * 64 + (t - 64)];
    __syncthreads();

    float biasv[4];
#pragma unroll
    for (int nt = 0; nt < 4; ++nt)
        biasv[nt] = sb[(isV ? 64 : 0) + nt * 16 + lane15];

    const float* gsrc = isV ? value : key;
    const int scol = pw * 16 + q4;        // s position (within 64-tile) of C rows

    // ---- load + project iter 0 -> buf 0 ----
    float4 f0, f1, f2, f3;
    {
        const size_t g = ((size_t)b * SS + chunk * 512 + pw * 16 + lane15) * 64 + q8;
        f0 = *reinterpret_cast<const float4*>(gsrc + g);
        f1 = *reinterpret_cast<const float4*>(gsrc + g + 4);
        f2 = *reinterpret_cast<const float4*>(gsrc + g + 32);
        f3 = *reinterpret_cast<const float4*>(gsrc + g + 36);
    }
    {
        short8 a0 = cvt8(f0, f1), a1 = cvt8(f2, f3);
        f32x4 cp[4];
#pragma unroll
        for (int nt = 0; nt < 4; ++nt) cp[nt] = (f32x4){0.f, 0.f, 0.f, 0.f};
#pragma unroll
        for (int nt = 0; nt < 4; ++nt) {
            cp[nt] = MFMA(a0, bw[0][nt], cp[nt]);
            cp[nt] = MFMA(a1, bw[1][nt], cp[nt]);
        }
#pragma unroll
        for (int nt = 0; nt < 4; ++nt) {
            const int x = nt * 16 + lane15;
            if (!isV) {
                short e[4];
#pragma unroll
                for (int r = 0; r < 4; ++r) e[r] = f2bf(elu1(cp[nt][r] + biasv[nt]));
                st4(&kT[0][x * 72 + scol], e[0], e[1], e[2], e[3]);
            } else {
                short ev[4], es[4];
#pragma unroll
                for (int r = 0; r < 4; ++r) {
                    float vv = cp[nt][r] + biasv[nt];
                    ev[r] = f2bf(vv);
                    es[r] = f2bf(vv * ssin[scol + r]);
                }
                st4(&vT[0][x * 72 + scol], ev[0], ev[1], ev[2], ev[3]);
                st4(&vsT[0][x * 72 + scol], es[0], es[1], es[2], es[3]);
            }
        }
    }
    __syncthreads();

    f32x4 cacc[4];
#pragma unroll
    for (int nt = 0; nt < 4; ++nt) cacc[nt] = (f32x4){0.f, 0.f, 0.f, 0.f};
    float aks = 0.f, akss = 0.f;

    for (int it = 0; it < 8; ++it) {
        const int p = it & 1;
        // prefetch next iter rows (latency overlapped with GEMM below)
        if (it < 7) {
            const size_t g = ((size_t)b * SS + chunk * 512 + (it + 1) * 64 + pw * 16 + lane15) * 64 + q8;
            f0 = *reinterpret_cast<const float4*>(gsrc + g);
            f1 = *reinterpret_cast<const float4*>(gsrc + g + 4);
            f2 = *reinterpret_cast<const float4*>(gsrc + g + 32);
            f3 = *reinterpret_cast<const float4*>(gsrc + g + 36);
        }
        // ---- kv / kvs GEMM from buf p: wave owns z-tile pw ----
        {
            const short* At = isV ? vsT[p] : vT[p];
            short8 a0 = *reinterpret_cast<const short8*>(&At[(pw * 16 + lane15) * 72 + q8]);
            short8 a1 = *reinterpret_cast<const short8*>(&At[(pw * 16 + lane15) * 72 + 32 + q8]);
#pragma unroll
            for (int nt = 0; nt < 4; ++nt) {
                short8 b0 = *reinterpret_cast<const short8*>(&kT[p][(nt * 16 + lane15) * 72 + q8]);
                short8 b1 = *reinterpret_cast<const short8*>(&kT[p][(nt * 16 + lane15) * 72 + 32 + q8]);
                cacc[nt] = MFMA(a0, b0, cacc[nt]);
                cacc[nt] = MFMA(a1, b1, cacc[nt]);
            }
        }
        // ---- ksum partials: lane -> x=l, wave -> s-range [w*8, +8) ----
        {
            short8 kk = *reinterpret_cast<const short8*>(&kT[p][l * 72 + w * 8]);
#pragma unroll
            for (int e = 0; e < 8; ++e) {
                float f = bf2f(kk[e]);
                aks += f;
                akss = fmaf(f, ssin[it * 64 + w * 8 + e], akss);
            }
        }
        // ---- project iter it+1 -> buf p^1 ----
        if (it < 7) {
            short8 a0 = cvt8(f0, f1), a1 = cvt8(f2, f3);
            f32x4 cp[4];
#pragma unroll
            for (int nt = 0; nt < 4; ++nt) cp[nt] = (f32x4){0.f, 0.f, 0.f, 0.f};
#pragma unroll
            for (int nt = 0; nt < 4; ++nt) {
                cp[nt] = MFMA(a0, bw[0][nt], cp[nt]);
                cp[nt] = MFMA(a1, bw[1][nt], cp[nt]);
            }
            const int pn = p ^ 1;
            const int sabs = (it + 1) * 64 + scol;
#pragma unroll
            for (int nt = 0; nt < 4; ++nt) {
                const int x = nt * 16 + lane15;
                if (!isV) {
                    short e[4];
#pragma unroll
                    for (int r = 0; r < 4; ++r) e[r] = f2bf(elu1(cp[nt][r] + biasv[nt]));
                    st4(&kT[pn][x * 72 + scol], e[0], e[1], e[2], e[3]);
                } else {
                    short ev[4], es[4];
#pragma unroll
                    for (int r = 0; r < 4; ++r) {
                        float vv = cp[nt][r] + biasv[nt];
                        ev[r] = f2bf(vv);
                        es[r] = f2bf(vv * ssin[sabs + r]);
                    }
                    st4(&vT[pn][x * 72 + scol], ev[0], ev[1], ev[2], ev[3]);
                    st4(&vsT[pn][x * 72 + scol], es[0], es[1], es[2], es[3]);
                }
            }
        }
        __syncthreads();
    }

    // ---- commit: coalesced non-atomic partial stores ----
    const int bh = b * HH + h;
    const size_t pbase = ((size_t)(chunk * 64) + bh) * 4096;
    float* dst = isV ? pkvs : pkv;
#pragma unroll
    for (int nt = 0; nt < 4; ++nt) {
        const int x = nt * 16 + lane15;
#pragma unroll
        for (int r = 0; r < 4; ++r) {
            const int z = pw * 16 + q4 + r;
            dst[pbase + z * 64 + x] = cacc[nt][r];
        }
    }
    sred[t] = aks; sred[512 + t] = akss;
    __syncthreads();
    if (t < 64) {
        float s = 0.f;
#pragma unroll
        for (int j = 0; j < 8; ++j) s += sred[j * 64 + t];
        pks[((size_t)(chunk * 64) + bh) * 128 + t] = s;
    } else if (t < 128) {
        const int tt = t - 64;
        float s = 0.f;
#pragma unroll
        for (int j = 0; j < 8; ++j) s += sred[512 + j * 64 + tt];
        pks[((size_t)(chunk * 64) + bh) * 128 + t] = s;
    }
}

// ---------------------------------------------------------------------------
// Reduce 8 chunk partials -> bf16 kv/kvs + fp32 ksums.
__global__ __launch_bounds__(256) void k_reduce(
    const float* __restrict__ pkv, const float* __restrict__ pkvs,
    const float* __restrict__ pks,
    short* __restrict__ kvb, short* __restrict__ kvsb,
    float* __restrict__ ksums)
{
    const int blk = blockIdx.x, t = threadIdx.x;
    if (blk < 512) {
        const float* src = (blk < 256) ? pkv : pkvs;
        short* dst = (blk < 256) ? kvb : kvsb;
        const int o4 = (blk & 255) * 256 + t;
        float4 s = make_float4(0.f, 0.f, 0.f, 0.f);
#pragma unroll
        for (int c = 0; c < 8; ++c) {
            float4 v = reinterpret_cast<const float4*>(src + (size_t)c * 262144)[o4];
            s.x += v.x; s.y += v.y; s.z += v.z; s.w += v.w;
        }
        st4(dst + (size_t)o4 * 4, f2bf(s.x), f2bf(s.y), f2bf(s.z), f2bf(s.w));
    } else {
        const int g = (blk - 512) * 256 + t;
        float4 s = make_float4(0.f, 0.f, 0.f, 0.f);
#pragma unroll
        for (int c = 0; c < 8; ++c) {
            float4 v = reinterpret_cast<const float4*>(pks + (size_t)c * 8192)[g];
            s.x += v.x; s.y += v.y; s.z += v.z; s.w += v.w;
        }
        reinterpret_cast<float4*>(ksums)[g] = s;
    }
}

// ---------------------------------------------------------------------------
// Phase 2: barrier-free head loop. Wave w owns heads {w, w+4, w+8, w+12} and
// computes full 16x64 tiles per head; C->A layout transforms go through a
// wave-PRIVATE LDS buffer (DS ops are in-order within a wave: no barrier).
// One final barrier for the 4-way cross-wave dense reduction.
__global__ __launch_bounds__(256, 3) void k_phase2(
    const float* __restrict__ query, const float* __restrict__ wq_b,
    const short* __restrict__ wqTb,
    const short* __restrict__ kvb, const short* __restrict__ kvsb,
    const float* __restrict__ ksums,
    const short* __restrict__ wdTb, const float* __restrict__ dense_b,
    float* __restrict__ out)
{
    const int st = blockIdx.x, b = blockIdx.y;
    const int s0 = st * 16;
    const int t = threadIdx.x, w = t >> 6, l = t & 63;
    const int lane15 = l & 15, q8 = (l >> 4) * 8, q4 = (l >> 4) * 4;

    __shared__ short sqin[16 * 72];          // q tile bf16, [s][d]
    __shared__ short wbuf[4][16 * 72];       // per-wave private transform buffer
    __shared__ float sbq[1024];              // all wq biases
    __shared__ float sksall[16 * 128];       // all heads' ksum|kssum
    __shared__ float scc[16];
    __shared__ float sdb[64];
    __shared__ float sred[4][16 * 68];       // cross-wave dense partials

    // ---- one-time staging ----
    if (t < 128) {
        int row = t >> 3, c8 = (t & 7) * 8;
        const float* qp = query + ((size_t)b * SS + s0 + row) * 64 + c8;
        float4 g0 = *reinterpret_cast<const float4*>(qp);
        float4 g1 = *reinterpret_cast<const float4*>(qp + 4);
        *reinterpret_cast<short8*>(&sqin[row * 72 + c8]) = cvt8(g0, g1);
    }
    for (int i = t; i < 1024; i += 256) sbq[i] = wq_b[i];
    {
        const float4* src = reinterpret_cast<const float4*>(ksums + (size_t)b * 2048);
        reinterpret_cast<float4*>(sksall)[t] = src[t];
        reinterpret_cast<float4*>(sksall)[t + 256] = src[t + 256];
    }
    if (t < 16) {
        float p = PI_C * (float)(s0 + t) * (1.f / 4096.f);
        scc[t] = __cosf(p) + __sinf(p);
    }
    if (t >= 192) sdb[t - 192] = dense_b[t - 192];
    __syncthreads();

    float ccr[4];
#pragma unroll
    for (int r = 0; r < 4; ++r) ccr[r] = scc[q4 + r];

    short* myb = &wbuf[w][0];
    f32x4 cd[4];
#pragma unroll
    for (int nt = 0; nt < 4; ++nt) cd[nt] = (f32x4){0.f, 0.f, 0.f, 0.f};

    for (int hh = 0; hh < 4; ++hh) {
        const int h = hh * 4 + w;
        const size_t bh = (size_t)(b * HH + h);
        const short* wqh = wqTb + (size_t)h * 4096;

        // ---- Q projection (full 16x64 tile for this wave's head) ----
        short8 aq0 = *reinterpret_cast<const short8*>(&sqin[lane15 * 72 + q8]);
        short8 aq1 = *reinterpret_cast<const short8*>(&sqin[lane15 * 72 + 32 + q8]);
        f32x4 cq[4];
#pragma unroll
        for (int nt = 0; nt < 4; ++nt) cq[nt] = (f32x4){0.f, 0.f, 0.f, 0.f};
#pragma unroll
        for (int nt = 0; nt < 4; ++nt) {
            short8 b0 = *reinterpret_cast<const short8*>(wqh + (nt * 16 + lane15) * 64 + q8);
            short8 b1 = *reinterpret_cast<const short8*>(wqh + (nt * 16 + lane15) * 64 + 32 + q8);
            cq[nt] = MFMA(aq0, b0, cq[nt]);
            cq[nt] = MFMA(aq1, b1, cq[nt]);
        }
        // ---- bias + elu, den partials, q' -> private LDS ----
        float dp[4] = {0.f, 0.f, 0.f, 0.f};
#pragma unroll
        for (int nt = 0; nt < 4; ++nt) {
            const int x = nt * 16 + lane15;
            const float bq = sbq[h * 64 + x];
            const float ksx = sksall[h * 128 + x];
            const float kssx = sksall[h * 128 + 64 + x];
#pragma unroll
            for (int r = 0; r < 4; ++r) {
                float qv = elu1(cq[nt][r] + bq);
                dp[r] = fmaf(qv, fmaf(ccr[r], kssx, ksx), dp[r]);
                myb[(q4 + r) * 72 + x] = f2bf(qv);
            }
        }
        // intra-quad butterfly (lane15 bits) -> full 64-x denominator per row
#pragma unroll
        for (int m = 1; m <= 8; m <<= 1) {
#pragma unroll
            for (int r = 0; r < 4; ++r) dp[r] += __shfl_xor(dp[r], m);
        }
        float invd[4];
#pragma unroll
        for (int r = 0; r < 4; ++r) invd[r] = 1.f / (dp[r] + 1e-5f);

        // ---- numerator GEMMs (A from private LDS; wave-ordered, no barrier) ----
        const short* kvh  = kvb  + bh * 4096;
        const short* kvsh = kvsb + bh * 4096;
        short8 a20 = *reinterpret_cast<const short8*>(&myb[lane15 * 72 + q8]);
        short8 a21 = *reinterpret_cast<const short8*>(&myb[lane15 * 72 + 32 + q8]);
        f32x4 ckv[4], ckvs[4];
#pragma unroll
        for (int nt = 0; nt < 4; ++nt) {
            ckv[nt] = (f32x4){0.f, 0.f, 0.f, 0.f};
            ckvs[nt] = (f32x4){0.f, 0.f, 0.f, 0.f};
        }
#pragma unroll
        for (int nt = 0; nt < 4; ++nt) {
            short8 b0 = *reinterpret_cast<const short8*>(kvh + (nt * 16 + lane15) * 64 + q8);
            short8 b1 = *reinterpret_cast<const short8*>(kvh + (nt * 16 + lane15) * 64 + 32 + q8);
            short8 c0 = *reinterpret_cast<const short8*>(kvsh + (nt * 16 + lane15) * 64 + q8);
            short8 c1 = *reinterpret_cast<const short8*>(kvsh + (nt * 16 + lane15) * 64 + 32 + q8);
            ckv[nt]  = MFMA(a20, b0, ckv[nt]);
            ckv[nt]  = MFMA(a21, b1, ckv[nt]);
            ckvs[nt] = MFMA(a20, c0, ckvs[nt]);
            ckvs[nt] = MFMA(a21, c1, ckvs[nt]);
        }
        // ---- combine + O -> private LDS (overwrites q'; wave-ordered) ----
#pragma unroll
        for (int nt = 0; nt < 4; ++nt) {
            const int z = nt * 16 + lane15;
#pragma unroll
            for (int r = 0; r < 4; ++r) {
                float o = fmaf(ccr[r], ckvs[nt][r], ckv[nt][r]) * invd[r];
                myb[(q4 + r) * 72 + z] = f2bf(o);
            }
        }
        // ---- dense GEMM, accumulate across this wave's heads ----
        const short* wdh = wdTb + (size_t)h * 4096;
        short8 a30 = *reinterpret_cast<const short8*>(&myb[lane15 * 72 + q8]);
        short8 a31 = *reinterpret_cast<const short8*>(&myb[lane15 * 72 + 32 + q8]);
#pragma unroll
        for (int nt = 0; nt < 4; ++nt) {
            short8 b0 = *reinterpret_cast<const short8*>(wdh + (nt * 16 + lane15) * 64 + q8);
            short8 b1 = *reinterpret_cast<const short8*>(wdh + (nt * 16 + lane15) * 64 + 32 + q8);
            cd[nt] = MFMA(a30, b0, cd[nt]);
            cd[nt] = MFMA(a31, b1, cd[nt]);
        }
    }

    // ---- cross-wave dense reduction + epilogue ----
#pragma unroll
    for (int nt = 0; nt < 4; ++nt) {
#pragma unroll
        for (int r = 0; r < 4; ++r)
            sred[w][(q4 + r) * 68 + nt * 16 + lane15] = cd[nt][r];
    }
    __syncthreads();
    {
        const int row = t >> 4, c0 = (t & 15) * 4;
        float4 s = make_float4(0.f, 0.f, 0.f, 0.f);
#pragma unroll
        for (int j = 0; j < 4; ++j) {
            float4 v = *reinterpret_cast<const float4*>(&sred[j][row * 68 + c0]);
            s.x += v.x; s.y += v.y; s.z += v.z; s.w += v.w;
        }
        float4 db = *reinterpret_cast<const float4*>(&sdb[c0]);
        s.x += db.x; s.y += db.y; s.z += db.z; s.w += db.w;
        *reinterpret_cast<float4*>(out + ((size_t)b * SS + s0 + row) * 64 + c0) = s;
    }
}

// ---------------------------------------------------------------------------
extern "C" void kernel_launch(void* const* d_in, const int* in_sizes, int n_in,
                              void* d_out, int out_size, void* d_ws, size_t ws_size,
                              hipStream_t stream) {
    const float* query   = (const float*)d_in[0];
    const float* key     = (const float*)d_in[1];
    const float* value   = (const float*)d_in[2];
    // d_in[3] attn_mask unused
    const float* wq_w    = (const float*)d_in[4];
    const float* wq_b    = (const float*)d_in[5];
    const float* wk_w    = (const float*)d_in[6];
    const float* wk_b    = (const float*)d_in[7];
    const float* wv_w    = (const float*)d_in[8];
    const float* wv_b    = (const float*)d_in[9];
    const float* dense_w = (const float*)d_in[10];
    const float* dense_b = (const float*)d_in[11];
    float* out = (float*)d_out;

    char* ws = (char*)d_ws;
    float* pkv   = (float*)(ws);
    float* pkvs  = (float*)(ws + 8388608);
    float* pks   = (float*)(ws + 16777216);
    short* kvb   = (short*)(ws + 17039360);
    short* kvsb  = (short*)(ws + 17563648);
    float* ksums = (float*)(ws + 18087936);
    short* wT    = (short*)(ws + 18120704);  // wq|wk|wv|wd, 65536 shorts each
    short* wqTb  = wT;
    short* wkTb  = wT + 65536;
    short* wvTb  = wT + 131072;
    short* wdTb  = wT + 196608;

    hipLaunchKernelGGL(k_prep, dim3(16, 4), dim3(256), 0, stream,
                       wq_w, wk_w, wv_w, dense_w, wT);
    hipLaunchKernelGGL(k_phase1, dim3(8, HH, BB), dim3(512), 0, stream,
                       key, value, wk_b, wv_b, wkTb, wvTb, pkv, pkvs, pks);
    hipLaunchKernelGGL(k_reduce, dim3(520), dim3(256), 0, stream,
                       pkv, pkvs, pks, kvb, kvsb, ksums);
    hipLaunchKernelGGL(k_phase2, dim3(256, BB), dim3(256), 0, stream,
                       query, wq_b, wqTb, kvb, kvsb, ksums, wdTb, dense_b, out);
}

// Round 5
// 185.929 us; speedup vs baseline: 1.1093x; 1.1093x over previous
//
#include <hip/hip_runtime.h>
#include <math.h>

// Problem constants
#define BB 4
#define SS 4096
#define DD 64
#define HH 16
#define PI_C 3.1415f

// ---------------------------------------------------------------------------
// ws layout (bytes):
//   0        : pkv   fp32 [8][64bh][z*64+x]   8,388,608   (phase1 partials)
//              pden  fp32 [4][b][s][64]      16,777,216   (OVERLAY: k_attn partials,
//   8388608  : pkvs  fp32 [8][64bh][z*64+x]   8,388,608    pkv/pkvs dead by then)
//   16777216 : pks   fp32 [8][64bh][128]        262,144   (ksum|kssum partials)
//   17039360 : kvb   bf16 [64bh][z*64+x]        524,288
//   17563648 : kvsb  bf16                       524,288
//   18087936 : ksums fp32 [64bh][128]            32,768
//   18120704 : wT    bf16 wq|wk|wv|wd x 65536   524,288
//   total ~18.6 MB
// ---------------------------------------------------------------------------

typedef __attribute__((ext_vector_type(8))) short short8;   // 8 x bf16 frag
typedef __attribute__((ext_vector_type(4))) float f32x4;    // MFMA C/D frag

#define MFMA(a, b, c) __builtin_amdgcn_mfma_f32_16x16x32_bf16(a, b, c, 0, 0, 0)

__device__ __forceinline__ short f2bf(float f) {
    union { float f; unsigned u; } v; v.f = f;
    unsigned r = v.u + 0x7FFFu + ((v.u >> 16) & 1u);   // round-to-nearest-even
    return (short)(r >> 16);
}
__device__ __forceinline__ float bf2f(short s) {
    union { unsigned u; float f; } v;
    v.u = ((unsigned)(unsigned short)s) << 16;
    return v.f;
}
__device__ __forceinline__ short8 cvt8(float4 a, float4 b) {
    short8 r;
    r[0] = f2bf(a.x); r[1] = f2bf(a.y); r[2] = f2bf(a.z); r[3] = f2bf(a.w);
    r[4] = f2bf(b.x); r[5] = f2bf(b.y); r[6] = f2bf(b.z); r[7] = f2bf(b.w);
    return r;
}
__device__ __forceinline__ float elu1(float x) { return x > 0.f ? x + 1.f : __expf(x); }
__device__ __forceinline__ void st4(short* p, short a, short b, short c, short d) {
    union { uint2 u; short s[4]; } x;
    x.s[0] = a; x.s[1] = b; x.s[2] = c; x.s[3] = d;
    *reinterpret_cast<uint2*>(p) = x.u;
}

// ---------------------------------------------------------------------------
// Transpose + bf16-convert weights into per-head [out_col][in_dim] layout.
__global__ __launch_bounds__(256) void k_prep(
    const float* __restrict__ wq, const float* __restrict__ wk,
    const float* __restrict__ wv, const float* __restrict__ wd,
    short* __restrict__ dst)
{
    const int h = blockIdx.x, y = blockIdx.y, t = threadIdx.x;
    const float* src = (y == 0) ? wq : (y == 1) ? wk : (y == 2) ? wv : wd;
    const int rs = (y < 3) ? 1024 : 64;
    const size_t srcbase = (y < 3) ? (size_t)(h * 64) : (size_t)(h * 4096);
    short* dm = dst + (size_t)y * 65536 + (size_t)h * 4096;
#pragma unroll
    for (int j = 0; j < 4; ++j) {
        int idx = j * 1024 + t * 4;
        int r = idx >> 6, c = idx & 63;
        float4 v = *reinterpret_cast<const float4*>(src + (size_t)r * rs + srcbase + c);
        dm[(c + 0) * 64 + r] = f2bf(v.x);
        dm[(c + 1) * 64 + r] = f2bf(v.y);
        dm[(c + 2) * 64 + r] = f2bf(v.z);
        dm[(c + 3) * 64 + r] = f2bf(v.w);
    }
}

// ---------------------------------------------------------------------------
// Phase 1 (round-3 version): project K,V (MFMA, weight B-frags in registers)
// -> transposed bf16 tiles in LDS -> kv/kvs GEMM with swapped operands
// (A=v, B=k') so the C-layout is [z][x], x=lane15 -> coalesced partial stores.
__global__ __launch_bounds__(256, 2) void k_phase1(
    const float* __restrict__ key, const float* __restrict__ value,
    const float* __restrict__ wk_b, const float* __restrict__ wv_b,
    const short* __restrict__ wkTb, const short* __restrict__ wvTb,
    float* __restrict__ pkv, float* __restrict__ pkvs,
    float* __restrict__ pks)
{
    const int chunk = blockIdx.x, h = blockIdx.y, b = blockIdx.z;
    const int t = threadIdx.x, w = t >> 6, l = t & 63;
    const int lane15 = l & 15, q8 = (l >> 4) * 8, q4 = (l >> 4) * 4;

    __shared__ short kT[64 * 72], vT[64 * 72], vsT[64 * 72];   // [x|z][s]
    __shared__ float ssin[512];
    __shared__ float sbk[64], sbv[64];
    __shared__ float sred[512];

    // projection weight B-frags -> registers (once per block, L2-hot)
    short8 bkf[2][4], bvf[2][4];
    {
        const short* wkh = wkTb + (size_t)h * 4096;
        const short* wvh = wvTb + (size_t)h * 4096;
#pragma unroll
        for (int kss = 0; kss < 2; ++kss)
#pragma unroll
            for (int nt = 0; nt < 4; ++nt) {
                bkf[kss][nt] = *reinterpret_cast<const short8*>(wkh + (nt * 16 + lane15) * 64 + kss * 32 + q8);
                bvf[kss][nt] = *reinterpret_cast<const short8*>(wvh + (nt * 16 + lane15) * 64 + kss * 32 + q8);
            }
    }
    ssin[t]       = __sinf(PI_C * (float)(chunk * 512 + t)       * (1.f / 4096.f));
    ssin[t + 256] = __sinf(PI_C * (float)(chunk * 512 + t + 256) * (1.f / 4096.f));
    if (t < 64) sbk[t] = wk_b[h * 64 + t];
    else if (t < 128) sbv[t - 64] = wv_b[h * 64 + (t - 64)];

    // prefetch K/V rows for iter 0
    float4 kf0, kf1, kf2, kf3, vf0, vf1, vf2, vf3;
    {
        const size_t g = ((size_t)b * SS + chunk * 512 + w * 16 + lane15) * 64 + q8;
        kf0 = *reinterpret_cast<const float4*>(key + g);
        kf1 = *reinterpret_cast<const float4*>(key + g + 4);
        kf2 = *reinterpret_cast<const float4*>(key + g + 32);
        kf3 = *reinterpret_cast<const float4*>(key + g + 36);
        vf0 = *reinterpret_cast<const float4*>(value + g);
        vf1 = *reinterpret_cast<const float4*>(value + g + 4);
        vf2 = *reinterpret_cast<const float4*>(value + g + 32);
        vf3 = *reinterpret_cast<const float4*>(value + g + 36);
    }

    f32x4 ckv[4], ckvs[4];
#pragma unroll
    for (int i = 0; i < 4; ++i) {
        ckv[i]  = (f32x4){0.f, 0.f, 0.f, 0.f};
        ckvs[i] = (f32x4){0.f, 0.f, 0.f, 0.f};
    }
    float aks = 0.f, akss = 0.f;
    __syncthreads();

    for (int it = 0; it < 8; ++it) {
        const int sbase = it * 64;
        // ---- projection: wave w handles rows [sbase + w*16, +16) ----
        f32x4 ckp[4], cvp[4];
#pragma unroll
        for (int i = 0; i < 4; ++i) {
            ckp[i] = (f32x4){0.f, 0.f, 0.f, 0.f};
            cvp[i] = (f32x4){0.f, 0.f, 0.f, 0.f};
        }
        {
            short8 ak0 = cvt8(kf0, kf1), ak1 = cvt8(kf2, kf3);
            short8 av0 = cvt8(vf0, vf1), av1 = cvt8(vf2, vf3);
#pragma unroll
            for (int nt = 0; nt < 4; ++nt) {
                ckp[nt] = MFMA(ak0, bkf[0][nt], ckp[nt]);
                cvp[nt] = MFMA(av0, bvf[0][nt], cvp[nt]);
                ckp[nt] = MFMA(ak1, bkf[1][nt], ckp[nt]);
                cvp[nt] = MFMA(av1, bvf[1][nt], cvp[nt]);
            }
        }
        // ---- bias + act + transposed bf16 stores ----
        const int srel = w * 16 + q4;
#pragma unroll
        for (int nt = 0; nt < 4; ++nt) {
            const int x = nt * 16 + lane15;
            const float bk = sbk[x], bv = sbv[x];
            short ek[4], ev[4], es[4];
#pragma unroll
            for (int r = 0; r < 4; ++r) {
                float kk = elu1(ckp[nt][r] + bk);
                float vv = cvp[nt][r] + bv;
                ek[r] = f2bf(kk);
                ev[r] = f2bf(vv);
                es[r] = f2bf(vv * ssin[sbase + srel + r]);
            }
            st4(&kT [x * 72 + srel], ek[0], ek[1], ek[2], ek[3]);
            st4(&vT [x * 72 + srel], ev[0], ev[1], ev[2], ev[3]);
            st4(&vsT[x * 72 + srel], es[0], es[1], es[2], es[3]);
        }
        __syncthreads();
        // ---- prefetch next iter's K/V (overlaps with kv GEMM below) ----
        if (it < 7) {
            const size_t g = ((size_t)b * SS + chunk * 512 + (it + 1) * 64 + w * 16 + lane15) * 64 + q8;
            kf0 = *reinterpret_cast<const float4*>(key + g);
            kf1 = *reinterpret_cast<const float4*>(key + g + 4);
            kf2 = *reinterpret_cast<const float4*>(key + g + 32);
            kf3 = *reinterpret_cast<const float4*>(key + g + 36);
            vf0 = *reinterpret_cast<const float4*>(value + g);
            vf1 = *reinterpret_cast<const float4*>(value + g + 4);
            vf2 = *reinterpret_cast<const float4*>(value + g + 32);
            vf3 = *reinterpret_cast<const float4*>(value + g + 36);
        }
        // ---- kv / kvs GEMM, swapped operands: A=v (m=z), B=k' (n=x) ----
#pragma unroll
        for (int kstep = 0; kstep < 2; ++kstep) {
            const int so = kstep * 32;
            short8 aV  = *reinterpret_cast<const short8*>(&vT [(w * 16 + lane15) * 72 + so + q8]);
            short8 aVS = *reinterpret_cast<const short8*>(&vsT[(w * 16 + lane15) * 72 + so + q8]);
#pragma unroll
            for (int nt = 0; nt < 4; ++nt) {
                short8 bK = *reinterpret_cast<const short8*>(&kT[(nt * 16 + lane15) * 72 + so + q8]);
                ckv[nt]  = MFMA(aV,  bK, ckv[nt]);
                ckvs[nt] = MFMA(aVS, bK, ckvs[nt]);
            }
        }
        // ---- ksum / kssum partials (thread: x = l, s-range [w*16,+16)) ----
        {
            short8 k0 = *reinterpret_cast<const short8*>(&kT[l * 72 + w * 16]);
            short8 k1 = *reinterpret_cast<const short8*>(&kT[l * 72 + w * 16 + 8]);
#pragma unroll
            for (int e = 0; e < 8; ++e) {
                float fa = bf2f(k0[e]), fb = bf2f(k1[e]);
                aks  += fa + fb;
                akss += fa * ssin[sbase + w * 16 + e] + fb * ssin[sbase + w * 16 + 8 + e];
            }
        }
        __syncthreads();
    }

    // ---- commit: coalesced non-atomic partial stores ([z][x], x = lane15) ----
    const int bh = b * HH + h;
    const size_t pbase = ((size_t)(chunk * 64) + bh) * 4096;
#pragma unroll
    for (int nt = 0; nt < 4; ++nt) {
        const int x = nt * 16 + lane15;
#pragma unroll
        for (int r = 0; r < 4; ++r) {
            const int z = w * 16 + q4 + r;
            pkv [pbase + z * 64 + x] = ckv[nt][r];
            pkvs[pbase + z * 64 + x] = ckvs[nt][r];
        }
    }
    sred[t] = aks; sred[256 + t] = akss;
    __syncthreads();
    if (t < 64) {
        pks[((size_t)(chunk * 64) + bh) * 128 + t] =
            sred[t] + sred[64 + t] + sred[128 + t] + sred[192 + t];
    } else if (t < 128) {
        int tt = t - 64;
        pks[((size_t)(chunk * 64) + bh) * 128 + t] =
            sred[256 + tt] + sred[320 + tt] + sred[384 + tt] + sred[448 + tt];
    }
}

// ---------------------------------------------------------------------------
// Reduce 8 chunk partials -> bf16 kv/kvs + fp32 ksums.
__global__ __launch_bounds__(256) void k_reduce(
    const float* __restrict__ pkv, const float* __restrict__ pkvs,
    const float* __restrict__ pks,
    short* __restrict__ kvb, short* __restrict__ kvsb,
    float* __restrict__ ksums)
{
    const int blk = blockIdx.x, t = threadIdx.x;
    if (blk < 512) {
        const float* src = (blk < 256) ? pkv : pkvs;
        short* dst = (blk < 256) ? kvb : kvsb;
        const int o4 = (blk & 255) * 256 + t;
        float4 s = make_float4(0.f, 0.f, 0.f, 0.f);
#pragma unroll
        for (int c = 0; c < 8; ++c) {
            float4 v = reinterpret_cast<const float4*>(src + (size_t)c * 262144)[o4];
            s.x += v.x; s.y += v.y; s.z += v.z; s.w += v.w;
        }
        st4(dst + (size_t)o4 * 4, f2bf(s.x), f2bf(s.y), f2bf(s.z), f2bf(s.w));
    } else {
        const int g = (blk - 512) * 256 + t;
        float4 s = make_float4(0.f, 0.f, 0.f, 0.f);
#pragma unroll
        for (int c = 0; c < 8; ++c) {
            float4 v = reinterpret_cast<const float4*>(pks + (size_t)c * 8192)[g];
            s.x += v.x; s.y += v.y; s.z += v.z; s.w += v.w;
        }
        reinterpret_cast<float4*>(ksums)[g] = s;
    }
}

// ---------------------------------------------------------------------------
// k_attn: grid (s-tile, head-group, b) = (256, 4, 4) = 4096 blocks.
// Each wave owns ONE head: q-proj -> elu/den -> num -> dense, one short
// chain, no mid-kernel barriers. One final barrier for the 4-way cross-wave
// reduce; block writes a 4-head dense partial to pden[group].
__global__ __launch_bounds__(256, 2) void k_attn(
    const float* __restrict__ query, const float* __restrict__ wq_b,
    const short* __restrict__ wqTb,
    const short* __restrict__ kvb, const short* __restrict__ kvsb,
    const float* __restrict__ ksums,
    const short* __restrict__ wdTb,
    float* __restrict__ pden)
{
    const int st = blockIdx.x, g = blockIdx.y, b = blockIdx.z;
    const int s0 = st * 16;
    const int t = threadIdx.x, w = t >> 6, l = t & 63;
    const int lane15 = l & 15, q8 = (l >> 4) * 8, q4 = (l >> 4) * 4;
    const int h = g * 4 + w;
    const size_t bh = (size_t)(b * HH + h);

    __shared__ short wbuf[4][16 * 72];       // per-wave private transform buffer
    __shared__ float sred[4][16 * 68];       // cross-wave dense partials

    short* myb = &wbuf[w][0];

    float ccr[4];
#pragma unroll
    for (int r = 0; r < 4; ++r) {
        float p = PI_C * (float)(s0 + q4 + r) * (1.f / 4096.f);
        ccr[r] = __cosf(p) + __sinf(p);
    }

    // ---- q A-frags direct from global (rows m=lane15) ----
    const float* qrow = query + ((size_t)b * SS + s0 + lane15) * 64;
    short8 aq0, aq1;
    {
        float4 f0 = *reinterpret_cast<const float4*>(qrow + q8);
        float4 f1 = *reinterpret_cast<const float4*>(qrow + q8 + 4);
        float4 f2 = *reinterpret_cast<const float4*>(qrow + 32 + q8);
        float4 f3 = *reinterpret_cast<const float4*>(qrow + 32 + q8 + 4);
        aq0 = cvt8(f0, f1);
        aq1 = cvt8(f2, f3);
    }

    // ---- Q projection (this wave's head, full 16x64) ----
    f32x4 cq[4];
#pragma unroll
    for (int nt = 0; nt < 4; ++nt) cq[nt] = (f32x4){0.f, 0.f, 0.f, 0.f};
    {
        const short* wqh = wqTb + (size_t)h * 4096;
#pragma unroll
        for (int nt = 0; nt < 4; ++nt) {
            short8 b0 = *reinterpret_cast<const short8*>(wqh + (nt * 16 + lane15) * 64 + q8);
            short8 b1 = *reinterpret_cast<const short8*>(wqh + (nt * 16 + lane15) * 64 + 32 + q8);
            cq[nt] = MFMA(aq0, b0, cq[nt]);
            cq[nt] = MFMA(aq1, b1, cq[nt]);
        }
    }

    // ---- bias + elu, den partials, q' -> private LDS (C-layout scatter) ----
    float dp[4] = {0.f, 0.f, 0.f, 0.f};
#pragma unroll
    for (int nt = 0; nt < 4; ++nt) {
        const int x = nt * 16 + lane15;
        const float bq = wq_b[h * 64 + x];
        const float ksx = ksums[bh * 128 + x];
        const float kssx = ksums[bh * 128 + 64 + x];
#pragma unroll
        for (int r = 0; r < 4; ++r) {
            float qv = elu1(cq[nt][r] + bq);
            dp[r] = fmaf(qv, fmaf(ccr[r], kssx, ksx), dp[r]);
            myb[(q4 + r) * 72 + x] = f2bf(qv);
        }
    }
#pragma unroll
    for (int m = 1; m <= 8; m <<= 1) {
#pragma unroll
        for (int r = 0; r < 4; ++r) dp[r] += __shfl_xor(dp[r], m);
    }
    float invd[4];
#pragma unroll
    for (int r = 0; r < 4; ++r) invd[r] = 1.f / (dp[r] + 1e-5f);

    // ---- q' A-frags (wave-private LDS; DS deps handled by lgkmcnt) ----
    short8 a20 = *reinterpret_cast<const short8*>(&myb[lane15 * 72 + q8]);
    short8 a21 = *reinterpret_cast<const short8*>(&myb[lane15 * 72 + 32 + q8]);

    // ---- numerator GEMMs (B-frags direct from global bf16 kv/kvs) ----
    f32x4 ckv[4], ckvs[4];
#pragma unroll
    for (int nt = 0; nt < 4; ++nt) {
        ckv[nt]  = (f32x4){0.f, 0.f, 0.f, 0.f};
        ckvs[nt] = (f32x4){0.f, 0.f, 0.f, 0.f};
    }
    {
        const short* kvh  = kvb  + bh * 4096;
        const short* kvsh = kvsb + bh * 4096;
#pragma unroll
        for (int nt = 0; nt < 4; ++nt) {
            short8 b0 = *reinterpret_cast<const short8*>(kvh + (nt * 16 + lane15) * 64 + q8);
            short8 b1 = *reinterpret_cast<const short8*>(kvh + (nt * 16 + lane15) * 64 + 32 + q8);
            short8 c0 = *reinterpret_cast<const short8*>(kvsh + (nt * 16 + lane15) * 64 + q8);
            short8 c1 = *reinterpret_cast<const short8*>(kvsh + (nt * 16 + lane15) * 64 + 32 + q8);
            ckv[nt]  = MFMA(a20, b0, ckv[nt]);
            ckv[nt]  = MFMA(a21, b1, ckv[nt]);
            ckvs[nt] = MFMA(a20, c0, ckvs[nt]);
            ckvs[nt] = MFMA(a21, c1, ckvs[nt]);
        }
    }

    // ---- combine + O -> private LDS (overwrites q'; wave-ordered) ----
#pragma unroll
    for (int nt = 0; nt < 4; ++nt) {
        const int z = nt * 16 + lane15;
#pragma unroll
        for (int r = 0; r < 4; ++r) {
            float o = fmaf(ccr[r], ckvs[nt][r], ckv[nt][r]) * invd[r];
            myb[(q4 + r) * 72 + z] = f2bf(o);
        }
    }
    short8 a30 = *reinterpret_cast<const short8*>(&myb[lane15 * 72 + q8]);
    short8 a31 = *reinterpret_cast<const short8*>(&myb[lane15 * 72 + 32 + q8]);

    // ---- dense GEMM (this head's 64-slice of K) ----
    f32x4 cd[4];
#pragma unroll
    for (int nt = 0; nt < 4; ++nt) cd[nt] = (f32x4){0.f, 0.f, 0.f, 0.f};
    {
        const short* wdh = wdTb + (size_t)h * 4096;
#pragma unroll
        for (int nt = 0; nt < 4; ++nt) {
            short8 b0 = *reinterpret_cast<const short8*>(wdh + (nt * 16 + lane15) * 64 + q8);
            short8 b1 = *reinterpret_cast<const short8*>(wdh + (nt * 16 + lane15) * 64 + 32 + q8);
            cd[nt] = MFMA(a30, b0, cd[nt]);
            cd[nt] = MFMA(a31, b1, cd[nt]);
        }
    }

    // ---- cross-wave (4-head) reduce -> group partial ----
#pragma unroll
    for (int nt = 0; nt < 4; ++nt) {
#pragma unroll
        for (int r = 0; r < 4; ++r)
            sred[w][(q4 + r) * 68 + nt * 16 + lane15] = cd[nt][r];
    }
    __syncthreads();
    {
        const int row = t >> 4, c0 = (t & 15) * 4;
        float4 s = make_float4(0.f, 0.f, 0.f, 0.f);
#pragma unroll
        for (int j = 0; j < 4; ++j) {
            float4 v = *reinterpret_cast<const float4*>(&sred[j][row * 68 + c0]);
            s.x += v.x; s.y += v.y; s.z += v.z; s.w += v.w;
        }
        *reinterpret_cast<float4*>(
            pden + (((size_t)(g * BB + b) * SS) + s0 + row) * 64 + c0) = s;
    }
}

// ---------------------------------------------------------------------------
// Final: sum the 4 head-group partials + dense bias -> out.
__global__ __launch_bounds__(256) void k_dfinal(
    const float* __restrict__ pden, const float* __restrict__ dense_b,
    float* __restrict__ out)
{
    const int i4 = blockIdx.x * 256 + threadIdx.x;   // float4 index, 0..262143
    const int c4 = i4 & 15;
    const int bb = i4 >> 16;
    const int rem = i4 & 65535;
    float4 s = *reinterpret_cast<const float4*>(dense_b + c4 * 4);
#pragma unroll
    for (int g = 0; g < 4; ++g) {
        float4 v = reinterpret_cast<const float4*>(pden)[(size_t)(g * BB + bb) * 65536 + rem];
        s.x += v.x; s.y += v.y; s.z += v.z; s.w += v.w;
    }
    reinterpret_cast<float4*>(out)[i4] = s;
}

// ---------------------------------------------------------------------------
extern "C" void kernel_launch(void* const* d_in, const int* in_sizes, int n_in,
                              void* d_out, int out_size, void* d_ws, size_t ws_size,
                              hipStream_t stream) {
    const float* query   = (const float*)d_in[0];
    const float* key     = (const float*)d_in[1];
    const float* value   = (const float*)d_in[2];
    // d_in[3] attn_mask unused
    const float* wq_w    = (const float*)d_in[4];
    const float* wq_b    = (const float*)d_in[5];
    const float* wk_w    = (const float*)d_in[6];
    const float* wk_b    = (const float*)d_in[7];
    const float* wv_w    = (const float*)d_in[8];
    const float* wv_b    = (const float*)d_in[9];
    const float* dense_w = (const float*)d_in[10];
    const float* dense_b = (const float*)d_in[11];
    float* out = (float*)d_out;

    char* ws = (char*)d_ws;
    float* pkv   = (float*)(ws);
    float* pkvs  = (float*)(ws + 8388608);
    float* pden  = (float*)(ws);             // overlay: pkv/pkvs dead after k_reduce
    float* pks   = (float*)(ws + 16777216);
    short* kvb   = (short*)(ws + 17039360);
    short* kvsb  = (short*)(ws + 17563648);
    float* ksums = (float*)(ws + 18087936);
    short* wT    = (short*)(ws + 18120704);  // wq|wk|wv|wd, 65536 shorts each
    short* wqTb  = wT;
    short* wkTb  = wT + 65536;
    short* wvTb  = wT + 131072;
    short* wdTb  = wT + 196608;

    hipLaunchKernelGGL(k_prep, dim3(16, 4), dim3(256), 0, stream,
                       wq_w, wk_w, wv_w, dense_w, wT);
    hipLaunchKernelGGL(k_phase1, dim3(8, HH, BB), dim3(256), 0, stream,
                       key, value, wk_b, wv_b, wkTb, wvTb, pkv, pkvs, pks);
    hipLaunchKernelGGL(k_reduce, dim3(520), dim3(256), 0, stream,
                       pkv, pkvs, pks, kvb, kvsb, ksums);
    hipLaunchKernelGGL(k_attn, dim3(SS / 16, 4, BB), dim3(256), 0, stream,
                       query, wq_b, wqTb, kvb, kvsb, ksums, wdTb, pden);
    hipLaunchKernelGGL(k_dfinal, dim3(1024), dim3(256), 0, stream,
                       pden, dense_b, out);
}